// Round 1
// baseline (241.023 us; speedup 1.0000x reference)
//
#include <hip/hip_runtime.h>
#include <hip/hip_bf16.h>

// ---------------- problem constants ----------------
#define BATCH   32768
#define DIM     512
#define H1N     128
#define H2N     256
#define NSUB    20
#define HID     32
#define NCLS    100
#define NHID    640            // NSUB*HID
#define TOTALP  19716          // 512*32 + 32 + 32*100 + 100
#define NPAR    394320         // NSUB*TOTALP
#define WS1P    16384
#define WS1B1   16416          // WS1+BS1
#define WS2END  19616          // WS1+BS1+WS2

// ---------------- ws layout (float units) ----------------
#define OFF_PART 0              // 256*512 partial col sums
#define OFF_H    131584         // 256 floats: hypernet h
#define OFF_W    131840         // 32 floats: softmax(ens_w)
#define OFF_PAR  131872         // 394320 floats: all_params
#define OFF_W1B  526192         // bf16 640*512   (163840 f32 slots)
#define OFF_B1   690032         // 640 f32
#define OFF_W2B  690672         // bf16 128*640   (40960 f32 slots)
#define OFF_BE   731632         // 128 f32
#define OFF_HH   731760         // bf16 32768*640 (10485760 f32 slots)

typedef __attribute__((ext_vector_type(8))) short short8;
typedef __attribute__((ext_vector_type(4))) float f32x4;

static __device__ inline unsigned short f2bf(float f) {
    __hip_bfloat16 h = __float2bfloat16(f);
    return *reinterpret_cast<unsigned short*>(&h);
}

// ---------------- K1: partial column sums of x ----------------
__global__ __launch_bounds__(256) void k1_colsum(const float* __restrict__ x, float* __restrict__ F) {
    int t = threadIdx.x, bid = blockIdx.x;
    const float* xb = x + (size_t)bid * 128 * DIM;
    float a0 = 0.f, a1 = 0.f;
    for (int r = 0; r < 128; ++r) {
        a0 += xb[r * DIM + t];
        a1 += xb[r * DIM + t + 256];
    }
    F[OFF_PART + bid * DIM + t]       = a0;
    F[OFF_PART + bid * DIM + t + 256] = a1;
}

// ---------------- K2: hypernet trunk (1 block) ----------------
__global__ __launch_bounds__(256) void k2_hyper(
    const float* __restrict__ Wh1, const float* __restrict__ bh1,
    const float* __restrict__ g1,  const float* __restrict__ be1,
    const float* __restrict__ Wh2, const float* __restrict__ bh2,
    const float* __restrict__ g2,  const float* __restrict__ be2,
    const float* __restrict__ ensw, float* __restrict__ F)
{
    __shared__ float sctx[DIM];
    __shared__ float sh1[H1N];
    __shared__ float sh2[H2N];
    int t = threadIdx.x;

    // reduce partial sums -> context mean
    for (int c = t; c < DIM; c += 256) {
        float s = 0.f;
        for (int b = 0; b < 256; ++b) s += F[OFF_PART + b * DIM + c];
        sctx[c] = s * (1.0f / (float)BATCH);
    }
    __syncthreads();

    // layer 1
    if (t < H1N) {
        float v = bh1[t];
        const float* w = Wh1 + t * DIM;
        for (int k = 0; k < DIM; ++k) v += sctx[k] * w[k];
        sh1[t] = v;
    }
    __syncthreads();
    {
        float mu = 0.f;
        for (int k = 0; k < H1N; ++k) mu += sh1[k];
        mu *= (1.0f / H1N);
        float var = 0.f;
        for (int k = 0; k < H1N; ++k) { float d = sh1[k] - mu; var += d * d; }
        var *= (1.0f / H1N);
        float inv = rsqrtf(var + 1e-5f);
        __syncthreads();
        if (t < H1N) {
            float v = (sh1[t] - mu) * inv * g1[t] + be1[t];
            sh1[t] = fmaxf(v, 0.f);
        }
        __syncthreads();
    }

    // layer 2
    {
        float v = bh2[t];
        const float* w = Wh2 + t * H1N;
        for (int k = 0; k < H1N; ++k) v += sh1[k] * w[k];
        sh2[t] = v;
    }
    __syncthreads();
    {
        float mu = 0.f;
        for (int k = 0; k < H2N; ++k) mu += sh2[k];
        mu *= (1.0f / H2N);
        float var = 0.f;
        for (int k = 0; k < H2N; ++k) { float d = sh2[k] - mu; var += d * d; }
        var *= (1.0f / H2N);
        float inv = rsqrtf(var + 1e-5f);
        float v = (sh2[t] - mu) * inv * g2[t] + be2[t];
        F[OFF_H + t] = fmaxf(v, 0.f);
    }

    // softmax over ens_w (20 values)
    if (t == 0) {
        float m = -1e30f;
        for (int s = 0; s < NSUB; ++s) m = fmaxf(m, ensw[s]);
        float sum = 0.f, e[NSUB];
        for (int s = 0; s < NSUB; ++s) { e[s] = __expf(ensw[s] - m); sum += e[s]; }
        for (int s = 0; s < NSUB; ++s) F[OFF_W + s] = e[s] / sum;
    }
}

// ---------------- K3: params = h @ W_h3^T + b_h3 (wave per row) ----------------
__global__ __launch_bounds__(256) void k3_gemv(
    const float* __restrict__ Wh3, const float* __restrict__ bh3, float* __restrict__ F)
{
    int t = threadIdx.x;
    int wid = t >> 6, lane = t & 63;
    size_t row = (size_t)blockIdx.x * 4 + wid;   // < 394320
    const float4 h = *(const float4*)(F + OFF_H + lane * 4);
    const float4 w = *(const float4*)(Wh3 + row * 256 + lane * 4);
    float d = w.x * h.x + w.y * h.y + w.z * h.z + w.w * h.w;
    for (int off = 32; off; off >>= 1) d += __shfl_down(d, off);
    if (lane == 0) F[OFF_PAR + row] = d + bh3[row];
}

// ---------------- K3b: reshuffle + bf16 convert ----------------
__global__ __launch_bounds__(256) void k3b_pack(float* __restrict__ F) {
    int j = blockIdx.x, t = threadIdx.x;     // j in [0,640)
    const float* PAR = F + OFF_PAR;
    __hip_bfloat16* W1B = (__hip_bfloat16*)(F + OFF_W1B);
    __hip_bfloat16* W2B = (__hip_bfloat16*)(F + OFF_W2B);
    int s = j >> 5, h = j & 31;
    const float* wsrc = PAR + s * TOTALP + h * DIM;
    for (int k = t; k < DIM; k += 256)
        W1B[j * DIM + k] = __float2bfloat16(wsrc[k]);
    if (t == 0)
        F[OFF_B1 + j] = PAR[s * TOTALP + WS1P + h];
    if (t < 128) {
        float v = 0.f;
        if (t < NCLS) v = F[OFF_W + s] * PAR[s * TOTALP + WS1B1 + t * HID + h];
        W2B[t * NHID + j] = __float2bfloat16(v);
    }
    if (j == 0 && t < 128) {
        float b = 0.f;
        if (t < NCLS)
            for (int ss = 0; ss < NSUB; ++ss)
                b += F[OFF_W + ss] * PAR[ss * TOTALP + WS2END + t];
        F[OFF_BE + t] = b;
    }
}

// ---------------- K4: MFMA bf16 GEMM, C = act(A @ Bw^T + bias) ----------------
// EPI=0: A=x f32 (ld 512), C=HH bf16 (ld 640), relu
// EPI=1: A=HH bf16 (ld 640), C=out f32 (ld 100, col<100 mask), no relu
template<int EPI>
__global__ __launch_bounds__(256) void gemm_k(
    const void* __restrict__ Ap, const __hip_bfloat16* __restrict__ Bw,
    const float* __restrict__ bias, void* __restrict__ Cp, int K, int nBN)
{
    __shared__ __align__(16) unsigned char sA[128 * 64 * 2];
    __shared__ __align__(16) unsigned char sB[128 * 64 * 2];
    const int t = threadIdx.x;
    const int bm = blockIdx.x / nBN, bn = blockIdx.x % nBN;
    const int Row0 = bm * 128, Col0 = bn * 128;
    const int wid = t >> 6, lane = t & 63;
    const int l16 = lane & 15, lq = lane >> 4;

    f32x4 acc[2][8];
    for (int a = 0; a < 2; ++a)
        for (int b = 0; b < 8; ++b)
            acc[a][b] = (f32x4){0.f, 0.f, 0.f, 0.f};

    for (int kc = 0; kc < K; kc += 64) {
        __syncthreads();
        // stage A tile (128 rows x 64 k), XOR-swizzled 16B units
        if (EPI == 0) {
            const float* x = (const float*)Ap;
            #pragma unroll
            for (int i = 0; i < 4; ++i) {
                int ul = t + i * 256, row = ul >> 3, uo = ul & 7;
                const float* src = x + (size_t)(Row0 + row) * 512 + kc + uo * 8;
                float4 a = *(const float4*)src;
                float4 b = *(const float4*)(src + 4);
                unsigned int p[4];
                p[0] = (unsigned)f2bf(a.x) | ((unsigned)f2bf(a.y) << 16);
                p[1] = (unsigned)f2bf(a.z) | ((unsigned)f2bf(a.w) << 16);
                p[2] = (unsigned)f2bf(b.x) | ((unsigned)f2bf(b.y) << 16);
                p[3] = (unsigned)f2bf(b.z) | ((unsigned)f2bf(b.w) << 16);
                *(uint4*)(sA + row * 128 + ((uo ^ (row & 7)) << 4)) = *(uint4*)p;
            }
        } else {
            const __hip_bfloat16* A = (const __hip_bfloat16*)Ap;
            #pragma unroll
            for (int i = 0; i < 4; ++i) {
                int ul = t + i * 256, row = ul >> 3, uo = ul & 7;
                uint4 v = *(const uint4*)(A + (size_t)(Row0 + row) * 640 + kc + uo * 8);
                *(uint4*)(sA + row * 128 + ((uo ^ (row & 7)) << 4)) = v;
            }
        }
        // stage B tile (128 weight-rows x 64 k)
        #pragma unroll
        for (int i = 0; i < 4; ++i) {
            int ul = t + i * 256, row = ul >> 3, uo = ul & 7;
            uint4 v = *(const uint4*)(Bw + (size_t)(Col0 + row) * K + kc + uo * 8);
            *(uint4*)(sB + row * 128 + ((uo ^ (row & 7)) << 4)) = v;
        }
        __syncthreads();

        #pragma unroll
        for (int kk = 0; kk < 2; ++kk) {
            const int u = kk * 4 + lq;
            short8 af[2], bfv[8];
            #pragma unroll
            for (int fm = 0; fm < 2; ++fm) {
                int row = wid * 32 + fm * 16 + l16;
                af[fm] = *(const short8*)(sA + row * 128 + ((u ^ (row & 7)) << 4));
            }
            #pragma unroll
            for (int fn = 0; fn < 8; ++fn) {
                int rw = fn * 16 + l16;
                bfv[fn] = *(const short8*)(sB + rw * 128 + ((u ^ (rw & 7)) << 4));
            }
            #pragma unroll
            for (int fm = 0; fm < 2; ++fm)
                #pragma unroll
                for (int fn = 0; fn < 8; ++fn)
                    acc[fm][fn] = __builtin_amdgcn_mfma_f32_16x16x32_bf16(
                        af[fm], bfv[fn], acc[fm][fn], 0, 0, 0);
        }
    }

    // epilogue
    #pragma unroll
    for (int fm = 0; fm < 2; ++fm) {
        #pragma unroll
        for (int fn = 0; fn < 8; ++fn) {
            int gcol = Col0 + fn * 16 + l16;
            float bv = bias[gcol];
            #pragma unroll
            for (int r = 0; r < 4; ++r) {
                int grow = Row0 + wid * 32 + fm * 16 + lq * 4 + r;
                float v = acc[fm][fn][r] + bv;
                if (EPI == 0) {
                    v = fmaxf(v, 0.f);
                    ((__hip_bfloat16*)Cp)[(size_t)grow * 640 + gcol] = __float2bfloat16(v);
                } else {
                    if (gcol < NCLS)
                        ((float*)Cp)[(size_t)grow * NCLS + gcol] = v;
                }
            }
        }
    }
}

// ---------------- launch ----------------
extern "C" void kernel_launch(void* const* d_in, const int* in_sizes, int n_in,
                              void* d_out, int out_size, void* d_ws, size_t ws_size,
                              hipStream_t stream)
{
    const float* x    = (const float*)d_in[0];
    const float* Wh1  = (const float*)d_in[1];
    const float* bh1  = (const float*)d_in[2];
    const float* g1   = (const float*)d_in[3];
    const float* be1  = (const float*)d_in[4];
    const float* Wh2  = (const float*)d_in[5];
    const float* bh2  = (const float*)d_in[6];
    const float* g2   = (const float*)d_in[7];
    const float* be2  = (const float*)d_in[8];
    const float* Wh3  = (const float*)d_in[9];
    const float* bh3  = (const float*)d_in[10];
    const float* ensw = (const float*)d_in[11];
    float* F = (float*)d_ws;
    float* out = (float*)d_out;

    __hip_bfloat16* W1B = (__hip_bfloat16*)(F + OFF_W1B);
    __hip_bfloat16* W2B = (__hip_bfloat16*)(F + OFF_W2B);
    __hip_bfloat16* HH  = (__hip_bfloat16*)(F + OFF_HH);

    k1_colsum<<<256, 256, 0, stream>>>(x, F);
    k2_hyper<<<1, 256, 0, stream>>>(Wh1, bh1, g1, be1, Wh2, bh2, g2, be2, ensw, F);
    k3_gemv<<<NPAR / 4, 256, 0, stream>>>(Wh3, bh3, F);
    k3b_pack<<<NHID, 256, 0, stream>>>(F);
    // stage 1: HH = relu(x @ W1all^T + b1all)   M=32768 N=640 K=512
    gemm_k<0><<<(BATCH / 128) * 5, 256, 0, stream>>>(x, W1B, F + OFF_B1, HH, 512, 5);
    // stage 2: out = HH @ W2eff^T + beff        M=32768 N=128(pad) K=640
    gemm_k<1><<<(BATCH / 128), 256, 0, stream>>>(HH, W2B, F + OFF_BE, out, 640, 1);
}

// Round 2
// 225.583 us; speedup vs baseline: 1.0684x; 1.0684x over previous
//
#include <hip/hip_runtime.h>
#include <hip/hip_bf16.h>

// ---------------- problem constants ----------------
#define BATCH   32768
#define DIM     512
#define H1N     128
#define H2N     256
#define NSUB    20
#define HID     32
#define NCLS    100
#define NHID    640            // NSUB*HID
#define TOTALP  19716          // 512*32 + 32 + 32*100 + 100
#define NPAR    394320         // NSUB*TOTALP
#define WS1P    16384
#define WS1B1   16416          // WS1+BS1
#define WS2END  19616          // WS1+BS1+WS2

// ---------------- ws layout (float units) ----------------
#define OFF_PART 0              // 256*512 partial col sums
#define OFF_H    131072         // 256 f32 hypernet h
#define OFF_W    131328         // 32 f32 softmax(ens_w)
#define OFF_B1   131360         // 640 f32
#define OFF_BE   132000         // 128 f32
#define OFF_B2R  132128         // 2000 f32 raw b2
#define OFF_W1B  134128         // bf16 640*512   (163840 f32 slots)
#define OFF_W2B  297968         // bf16 128*640   (40960 f32 slots)
#define OFF_XB   338928         // bf16 32768*512 (8388608 f32 slots)
#define OFF_HH   8727536        // bf16 32768*640 (10485760 f32 slots)

typedef __attribute__((ext_vector_type(8))) short short8;
typedef __attribute__((ext_vector_type(4))) float f32x4;

static __device__ inline unsigned short f2bf(float f) {
    __hip_bfloat16 h = __float2bfloat16(f);
    return *reinterpret_cast<unsigned short*>(&h);
}

static __device__ __forceinline__ void gload16(const void* g, void* l) {
    __builtin_amdgcn_global_load_lds(
        (const __attribute__((address_space(1))) void*)g,
        (__attribute__((address_space(3))) void*)l, 16, 0, 0);
}

// ---------------- K1: partial column sums + bf16 convert of x ----------------
__global__ __launch_bounds__(256) void k1_colsum(const float* __restrict__ x,
                                                 float* __restrict__ F) {
    int t = threadIdx.x, bid = blockIdx.x;
    const float* xb = x + (size_t)bid * 128 * DIM;
    unsigned short* ob = (unsigned short*)(F + OFF_XB) + (size_t)bid * 128 * DIM;
    float a0 = 0.f, a1 = 0.f;
    for (int r = 0; r < 128; ++r) {
        float2 v = *(const float2*)(xb + r * DIM + t * 2);
        a0 += v.x; a1 += v.y;
        ushort2 u; u.x = f2bf(v.x); u.y = f2bf(v.y);
        *(ushort2*)(ob + r * DIM + t * 2) = u;
    }
    *(float2*)(F + OFF_PART + bid * DIM + t * 2) = make_float2(a0, a1);
}

// ---------------- K2: hypernet trunk (1 block) ----------------
__global__ __launch_bounds__(256) void k2_hyper(
    const float* __restrict__ Wh1, const float* __restrict__ bh1,
    const float* __restrict__ g1,  const float* __restrict__ be1,
    const float* __restrict__ Wh2, const float* __restrict__ bh2,
    const float* __restrict__ g2,  const float* __restrict__ be2,
    const float* __restrict__ ensw, float* __restrict__ F)
{
    __shared__ __align__(16) float sctx[DIM];
    __shared__ __align__(16) float sh1[H1N];
    __shared__ __align__(16) float sh2[H2N];
    int t = threadIdx.x;

    for (int c = t; c < DIM; c += 256) {
        float s = 0.f;
        for (int b = 0; b < 256; ++b) s += F[OFF_PART + b * DIM + c];
        sctx[c] = s * (1.0f / (float)BATCH);
    }
    __syncthreads();

    // layer 1
    if (t < H1N) {
        float v = bh1[t];
        const float4* w = (const float4*)(Wh1 + t * DIM);
        for (int k = 0; k < DIM / 4; ++k) {
            float4 ww = w[k]; float4 c = *(const float4*)(sctx + k * 4);
            v += ww.x * c.x + ww.y * c.y + ww.z * c.z + ww.w * c.w;
        }
        sh1[t] = v;
    }
    __syncthreads();
    {
        float mu = 0.f;
        for (int k = 0; k < H1N; ++k) mu += sh1[k];
        mu *= (1.0f / H1N);
        float var = 0.f;
        for (int k = 0; k < H1N; ++k) { float d = sh1[k] - mu; var += d * d; }
        var *= (1.0f / H1N);
        float inv = rsqrtf(var + 1e-5f);
        __syncthreads();
        if (t < H1N) {
            float v = (sh1[t] - mu) * inv * g1[t] + be1[t];
            sh1[t] = fmaxf(v, 0.f);
        }
        __syncthreads();
    }

    // layer 2
    {
        float v = bh2[t];
        const float4* w = (const float4*)(Wh2 + t * H1N);
        for (int k = 0; k < H1N / 4; ++k) {
            float4 ww = w[k]; float4 c = *(const float4*)(sh1 + k * 4);
            v += ww.x * c.x + ww.y * c.y + ww.z * c.z + ww.w * c.w;
        }
        sh2[t] = v;
    }
    __syncthreads();
    {
        float mu = 0.f;
        for (int k = 0; k < H2N; ++k) mu += sh2[k];
        mu *= (1.0f / H2N);
        float var = 0.f;
        for (int k = 0; k < H2N; ++k) { float d = sh2[k] - mu; var += d * d; }
        var *= (1.0f / H2N);
        float inv = rsqrtf(var + 1e-5f);
        float v = (sh2[t] - mu) * inv * g2[t] + be2[t];
        F[OFF_H + t] = fmaxf(v, 0.f);
    }

    if (t == 0) {
        float m = -1e30f;
        for (int s = 0; s < NSUB; ++s) m = fmaxf(m, ensw[s]);
        float sum = 0.f, e[NSUB];
        for (int s = 0; s < NSUB; ++s) { e[s] = __expf(ensw[s] - m); sum += e[s]; }
        for (int s = 0; s < NSUB; ++s) F[OFF_W + s] = e[s] / sum;
    }
}

// ---------------- K3: params GEMV fused with pack/convert ----------------
__global__ __launch_bounds__(256) void k3_gemv(
    const float* __restrict__ Wh3, const float* __restrict__ bh3, float* __restrict__ F)
{
    int t = threadIdx.x;
    int wid = t >> 6, lane = t & 63;
    int row = blockIdx.x * 4 + wid;   // < 394320
    const float4 h = *(const float4*)(F + OFF_H + lane * 4);
    const float4 w = *(const float4*)(Wh3 + (size_t)row * 256 + lane * 4);
    float d = w.x * h.x + w.y * h.y + w.z * h.z + w.w * h.w;
    for (int off = 32; off; off >>= 1) d += __shfl_down(d, off);
    if (lane == 0) {
        float val = d + bh3[row];
        int s = row / TOTALP;
        int r = row - s * TOTALP;
        __hip_bfloat16* W1B = (__hip_bfloat16*)(F + OFF_W1B);
        __hip_bfloat16* W2B = (__hip_bfloat16*)(F + OFF_W2B);
        if (r < WS1P) {
            int hh = r >> 9, k = r & 511;
            W1B[(s * HID + hh) * DIM + k] = __float2bfloat16(val);
        } else if (r < WS1B1) {
            F[OFF_B1 + s * HID + (r - WS1P)] = val;
        } else if (r < WS2END) {
            int q = r - WS1B1; int c = q >> 5, hh = q & 31;
            float ws = F[OFF_W + s];
            W2B[c * NHID + s * HID + hh] = __float2bfloat16(ws * val);
        } else {
            F[OFF_B2R + s * NCLS + (r - WS2END)] = val;
        }
    }
}

// ---------------- K4: b2 ensemble reduce + W2B pad-row zero ----------------
__global__ __launch_bounds__(256) void k4_be(float* __restrict__ F) {
    int t = threadIdx.x;
    if (t < 128) {
        float b = 0.f;
        if (t < NCLS)
            for (int s = 0; s < NSUB; ++s)
                b += F[OFF_W + s] * F[OFF_B2R + s * NCLS + t];
        F[OFF_BE + t] = b;
    }
    __hip_bfloat16* W2B = (__hip_bfloat16*)(F + OFF_W2B);
    for (int i = t; i < 28 * NHID; i += 256) {
        int rr = NCLS + i / NHID, cc = i % NHID;
        W2B[rr * NHID + cc] = __float2bfloat16(0.f);
    }
}

// ---------------- K5: MFMA bf16 GEMM, C = act(A @ Bw^T + bias) ----------------
// BM = MR*64 rows per block, BN = 128, BK = 64. global_load_lds staging with
// pre-swizzled global source (linear LDS dest), XOR-swizzled ds_read.
// EPI=0: C bf16 ld 640, relu.  EPI=1: C f32 ld 100, col<100 mask.
template<int EPI, int MR>
__global__ __launch_bounds__(256) void gemm_k(
    const __hip_bfloat16* __restrict__ A, const __hip_bfloat16* __restrict__ Bw,
    const float* __restrict__ bias, void* __restrict__ Cp, int K, int lda, int nBN)
{
    __shared__ __align__(16) unsigned char sA[MR * 64 * 128];
    __shared__ __align__(16) unsigned char sB[128 * 128];
    const int t = threadIdx.x;
    // XCD-chunked swizzle (grid divisible by 8)
    int bid = blockIdx.x;
    const int cpx = gridDim.x >> 3;
    bid = (bid & 7) * cpx + (bid >> 3);
    const int bm = bid / nBN, bn = bid % nBN;
    const int Row0 = bm * (MR * 64), Col0 = bn * 128;
    const int wid = t >> 6, lane = t & 63;
    const int l16 = lane & 15, lq = lane >> 4;

    f32x4 acc[MR][8];
    #pragma unroll
    for (int a = 0; a < MR; ++a)
        #pragma unroll
        for (int b = 0; b < 8; ++b)
            acc[a][b] = (f32x4){0.f, 0.f, 0.f, 0.f};

    for (int kc = 0; kc < K; kc += 64) {
        __syncthreads();
        // A tile: MR*64 rows x 64 k  = MR*512 16B-units, linear LDS,
        // inverse-swizzled global source
        #pragma unroll
        for (int i = 0; i < MR * 2; ++i) {
            int cidx = wid * (MR * 2) + i;
            int ul = cidx * 64 + lane;
            int row = ul >> 3, u = ul & 7;
            const __hip_bfloat16* src =
                A + (size_t)(Row0 + row) * lda + kc + ((u ^ (row & 7)) << 3);
            gload16(src, sA + cidx * 1024);
        }
        // B tile: 128 rows x 64 k
        #pragma unroll
        for (int i = 0; i < 4; ++i) {
            int cidx = wid * 4 + i;
            int ul = cidx * 64 + lane;
            int row = ul >> 3, u = ul & 7;
            const __hip_bfloat16* src =
                Bw + (size_t)(Col0 + row) * K + kc + ((u ^ (row & 7)) << 3);
            gload16(src, sB + cidx * 1024);
        }
        __syncthreads();

        #pragma unroll
        for (int kk = 0; kk < 2; ++kk) {
            const int u = kk * 4 + lq;
            short8 af[MR], bfv[8];
            #pragma unroll
            for (int fm = 0; fm < MR; ++fm) {
                int row = wid * (MR * 16) + fm * 16 + l16;
                af[fm] = *(const short8*)(sA + row * 128 + ((u ^ (row & 7)) << 4));
            }
            #pragma unroll
            for (int fn = 0; fn < 8; ++fn) {
                int rw = fn * 16 + l16;
                bfv[fn] = *(const short8*)(sB + rw * 128 + ((u ^ (rw & 7)) << 4));
            }
            #pragma unroll
            for (int fm = 0; fm < MR; ++fm)
                #pragma unroll
                for (int fn = 0; fn < 8; ++fn)
                    acc[fm][fn] = __builtin_amdgcn_mfma_f32_16x16x32_bf16(
                        af[fm], bfv[fn], acc[fm][fn], 0, 0, 0);
        }
    }

    #pragma unroll
    for (int fm = 0; fm < MR; ++fm) {
        #pragma unroll
        for (int fn = 0; fn < 8; ++fn) {
            int gcol = Col0 + fn * 16 + l16;
            float bv = bias[gcol];
            #pragma unroll
            for (int r = 0; r < 4; ++r) {
                int grow = Row0 + wid * (MR * 16) + fm * 16 + lq * 4 + r;
                float v = acc[fm][fn][r] + bv;
                if (EPI == 0) {
                    v = fmaxf(v, 0.f);
                    ((__hip_bfloat16*)Cp)[(size_t)grow * NHID + gcol] = __float2bfloat16(v);
                } else {
                    if (gcol < NCLS)
                        ((float*)Cp)[(size_t)grow * NCLS + gcol] = v;
                }
            }
        }
    }
}

// ---------------- launch ----------------
extern "C" void kernel_launch(void* const* d_in, const int* in_sizes, int n_in,
                              void* d_out, int out_size, void* d_ws, size_t ws_size,
                              hipStream_t stream)
{
    const float* x    = (const float*)d_in[0];
    const float* Wh1  = (const float*)d_in[1];
    const float* bh1  = (const float*)d_in[2];
    const float* g1   = (const float*)d_in[3];
    const float* be1  = (const float*)d_in[4];
    const float* Wh2  = (const float*)d_in[5];
    const float* bh2  = (const float*)d_in[6];
    const float* g2   = (const float*)d_in[7];
    const float* be2  = (const float*)d_in[8];
    const float* Wh3  = (const float*)d_in[9];
    const float* bh3  = (const float*)d_in[10];
    const float* ensw = (const float*)d_in[11];
    float* F = (float*)d_ws;
    float* out = (float*)d_out;

    const __hip_bfloat16* XB  = (const __hip_bfloat16*)(F + OFF_XB);
    const __hip_bfloat16* W1B = (const __hip_bfloat16*)(F + OFF_W1B);
    const __hip_bfloat16* W2B = (const __hip_bfloat16*)(F + OFF_W2B);
    __hip_bfloat16* HH = (__hip_bfloat16*)(F + OFF_HH);

    k1_colsum<<<256, 256, 0, stream>>>(x, F);
    k2_hyper<<<1, 256, 0, stream>>>(Wh1, bh1, g1, be1, Wh2, bh2, g2, be2, ensw, F);
    k3_gemv<<<NPAR / 4, 256, 0, stream>>>(Wh3, bh3, F);
    k4_be<<<1, 256, 0, stream>>>(F);
    // stage 1: HH = relu(xb @ W1all^T + b1all)   M=32768 N=640 K=512
    gemm_k<0, 2><<<(BATCH / 128) * 5, 256, 0, stream>>>(XB, W1B, F + OFF_B1, HH, 512, 512, 5);
    // stage 2: out = HH @ W2eff^T + beff         M=32768 N=128(pad) K=640
    gemm_k<1, 1><<<(BATCH / 64), 256, 0, stream>>>(HH, W2B, F + OFF_BE, out, 640, 640, 1);
}